// Round 8
// baseline (418.116 us; speedup 1.0000x reference)
//
#include <hip/hip_runtime.h>

#define TT 512
#define HH 32

typedef _Float16 half2_t __attribute__((ext_vector_type(2)));

__device__ __forceinline__ float fast_exp2(float v) { return __builtin_amdgcn_exp2f(v); }
__device__ __forceinline__ float fast_rcp(float v)  { return __builtin_amdgcn_rcpf(v); }

__device__ __forceinline__ float sigmoid_f(float v) {
    return fast_rcp(1.0f + fast_exp2(-1.442695040888963f * v));
}

__device__ __forceinline__ half2_t u2h(unsigned u) { return __builtin_bit_cast(half2_t, u); }

// DPP move: permute within rows/quads on the VALU pipe (no LDS).
// CTRL must be a compile-time immediate -> template parameter.
template <int CTRL>
__device__ __forceinline__ unsigned dppmov(unsigned v) {
    return (unsigned)__builtin_amdgcn_update_dpp((int)v, (int)v, CTRL, 0xF, 0xF, false);
}
#define DPP_XOR1 0xB1   // quad_perm [1,0,3,2]
#define DPP_XOR2 0x4E   // quad_perm [2,3,0,1]
#define DPP_ROR4 0x124  // row_ror:4  (within 16-lane row)
#define DPP_ROR8 0x128  // row_ror:8

#if __has_builtin(__builtin_amdgcn_permlane16_swap)
#define HAVE_PL16 1
#else
#define HAVE_PL16 0
#endif
#if __has_builtin(__builtin_amdgcn_permlane32_swap)
#define HAVE_PL32 1
#else
#define HAVE_PL32 0
#endif

// All-gather: input = one 32-bit word per lane; output = 16 words covering all
// 32 h units, in a lane-dependent but DETERMINISTIC order. The same network is
// run on index probes at init, so the order never needs to be known analytically.
__device__ __forceinline__ void allgather16(unsigned w, unsigned out[16]) {
    unsigned v0 = w;
    unsigned v1 = dppmov<DPP_XOR2>(v0);
    unsigned v2 = dppmov<DPP_ROR4>(v0);
    unsigned v3 = dppmov<DPP_ROR4>(v1);
    unsigned v4 = dppmov<DPP_ROR8>(v0);
    unsigned v5 = dppmov<DPP_ROR8>(v1);
    unsigned v6 = dppmov<DPP_ROR8>(v2);
    unsigned v7 = dppmov<DPP_ROR8>(v3);
    unsigned vv[8] = {v0, v1, v2, v3, v4, v5, v6, v7};
#pragma unroll
    for (int s = 0; s < 8; ++s) {
#if HAVE_PL16
        auto r = __builtin_amdgcn_permlane16_swap(vv[s], vv[s], false, false);
        out[2 * s + 0] = (unsigned)r[0];
        out[2 * s + 1] = (unsigned)r[1];
#else
        out[2 * s + 0] = vv[s];
        out[2 * s + 1] = (unsigned)__shfl_xor((int)vv[s], 16);
#endif
    }
}

__global__ __launch_bounds__(256, 4) void lstm_fused_kernel(
    const float* __restrict__ x,     // [B, T, 1]
    const float* __restrict__ wih,   // [128, 1]
    const float* __restrict__ whh,   // [128, 32]
    const float* __restrict__ bih,   // [128]
    const float* __restrict__ bhh,   // [128]
    const float* __restrict__ fc1w,  // [16, 32]
    const float* __restrict__ fc1b,  // [16]
    const float* __restrict__ fc2w,  // [1, 16]
    const float* __restrict__ fc2b,  // [1]
    float* __restrict__ out)         // [B, 1]
{
    __shared__ float lds_x[4][TT];

    const int wave = threadIdx.x >> 6;
    const int lane = threadIdx.x & 63;
    const int b = blockIdx.x * 4 + wave;

    // ---- stage x[b][0..511] into LDS (coalesced float4) ----
    {
        const float4* xv = reinterpret_cast<const float4*>(x + (size_t)b * TT);
        float4* lv = reinterpret_cast<float4*>(&lds_x[wave][0]);
        lv[lane]      = xv[lane];
        lv[lane + 64] = xv[lane + 64];
    }

    // ---- calibrate the gather network: probe with packed unit indices ----
    unsigned pidx[16];
    {
        unsigned ps = (unsigned)(lane & 31);
        unsigned pn = dppmov<DPP_XOR1>(ps);
        allgather16(ps | (pn << 16), pidx);
    }

#if HAVE_PL32
    bool x32_r0_is_partner;
    {
        auto t = __builtin_amdgcn_permlane32_swap((unsigned)lane, (unsigned)lane, false, false);
        x32_r0_is_partner = ((unsigned)t[0] == ((unsigned)lane ^ 32u));
    }
#endif

    // ---- per-lane gate rows: g0 = lane (i/f rows), g1 = lane+64 (g/o rows) ----
    const int g0 = lane;
    const int g1 = lane + 64;

    // pack W_hh in the calibrated word order; pin in VGPRs
    unsigned w0u[16], w1u[16];
    {
        const float* r0 = whh + g0 * HH;
        const float* r1 = whh + g1 * HH;
#pragma unroll
        for (int s = 0; s < 16; ++s) {
            const unsigned ua = pidx[s] & 0xFFFFu;
            const unsigned ub = pidx[s] >> 16;
            half2_t a; a[0] = (_Float16)r0[ua]; a[1] = (_Float16)r0[ub];
            w0u[s] = __builtin_bit_cast(unsigned, a);
            half2_t d; d[0] = (_Float16)r1[ua]; d[1] = (_Float16)r1[ub];
            w1u[s] = __builtin_bit_cast(unsigned, d);
        }
    }
#pragma unroll
    for (int k = 0; k < 16; ++k) {
        asm volatile("" : "+v"(w0u[k]));
        asm volatile("" : "+v"(w1u[k]));
    }

    const float wi0   = wih[g0];
    const float wi1   = wih[g1];
    const float bias0 = bih[g0] + bhh[g0];
    const float bias1 = bih[g1] + bhh[g1];

    const bool lo = (lane < HH);
    const float kk = lo ? -2.885390081777927f : -1.442695040888963f;
    const float sc = lo ? 2.0f : 1.0f;
    const float ad = lo ? -1.0f : 0.0f;

    float hn = 0.0f;   // this lane's h[lane&31] (mirrored across wave halves)
    float c  = 0.0f;

    __syncthreads();

#pragma unroll 1
    for (int t = 0; t < TT; ++t) {
        // ---- pack h pair and all-gather in registers (no LDS) ----
        unsigned hh[16];
        {
            const unsigned hnb_u = dppmov<DPP_XOR1>(__builtin_bit_cast(unsigned, hn));
            const float hnb = __builtin_bit_cast(float, hnb_u);
            auto pk = __builtin_amdgcn_cvt_pkrtz(hn, hnb);   // (self, neighbor) fp16
            allgather16(__builtin_bit_cast(unsigned, pk), hh);
        }

        const float xt = lds_x[wave][t];
        float acc0a = __builtin_fmaf(xt, wi0, bias0);
        float acc1a = __builtin_fmaf(xt, wi1, bias1);
        float acc0b = 0.0f, acc1b = 0.0f;
#pragma unroll
        for (int k = 0; k < 8; ++k) {
            acc0a = __builtin_amdgcn_fdot2(u2h(hh[k]), u2h(w0u[k]), acc0a, false);
            acc1a = __builtin_amdgcn_fdot2(u2h(hh[k]), u2h(w1u[k]), acc1a, false);
        }
#pragma unroll
        for (int k = 8; k < 16; ++k) {
            acc0b = __builtin_amdgcn_fdot2(u2h(hh[k]), u2h(w0u[k]), acc0b, false);
            acc1b = __builtin_amdgcn_fdot2(u2h(hh[k]), u2h(w1u[k]), acc1b, false);
        }
        const float acc0 = acc0a + acc0b;
        const float acc1 = acc1a + acc1b;

        // activations: acc0 -> sigmoid (i or f); acc1 -> tanh(g) / sigmoid(o)
        const float a0 = sigmoid_f(acc0);
        const float a1 = __builtin_fmaf(sc, fast_rcp(1.0f + fast_exp2(kk * acc1)), ad);

        // exchange halves lane j <-> j+32 on the VALU pipe
#if HAVE_PL32
        float p0, p1;
        {
            auto r0p = __builtin_amdgcn_permlane32_swap(
                __builtin_bit_cast(unsigned, a0), __builtin_bit_cast(unsigned, a0), false, false);
            p0 = __builtin_bit_cast(float, x32_r0_is_partner ? (unsigned)r0p[0] : (unsigned)r0p[1]);
            auto r1p = __builtin_amdgcn_permlane32_swap(
                __builtin_bit_cast(unsigned, a1), __builtin_bit_cast(unsigned, a1), false, false);
            p1 = __builtin_bit_cast(float, x32_r0_is_partner ? (unsigned)r1p[0] : (unsigned)r1p[1]);
        }
#else
        const float p0 = __shfl_xor(a0, 32);
        const float p1 = __shfl_xor(a1, 32);
#endif
        const float i_ = lo ? a0 : p0;
        const float f_ = lo ? p0 : a0;
        const float g_ = lo ? a1 : p1;
        const float o_ = lo ? p1 : a1;

        c = __builtin_fmaf(f_, c, i_ * g_);
        const float e = fast_exp2(-2.885390081777927f * c);
        hn = __builtin_fmaf(2.0f * o_, fast_rcp(1.0f + e), -o_);
    }

    // ---- final h distribution for the MLP head ----
    unsigned hf[16];
    {
        const unsigned hnb_u = dppmov<DPP_XOR1>(__builtin_bit_cast(unsigned, hn));
        const float hnb = __builtin_bit_cast(float, hnb_u);
        auto pk = __builtin_amdgcn_cvt_pkrtz(hn, hnb);
        allgather16(__builtin_bit_cast(unsigned, pk), hf);
    }

    // ---- MLP head: z = relu(h@fc1w.T + fc1b); out = z@fc2w.T + fc2b ----
    float val = 0.0f;
    if (lane < 16) {
        float acc = fc1b[lane];
        const float* fw = fc1w + lane * HH;
#pragma unroll
        for (int s = 0; s < 16; ++s) {
            const unsigned ua = pidx[s] & 0xFFFFu;
            const unsigned ub = pidx[s] >> 16;
            half2_t h2 = u2h(hf[s]);
            acc = __builtin_fmaf((float)h2[0], fw[ua], acc);
            acc = __builtin_fmaf((float)h2[1], fw[ub], acc);
        }
        val = fmaxf(acc, 0.0f) * fc2w[lane];
    }
#pragma unroll
    for (int off = 8; off; off >>= 1) val += __shfl_down(val, off);
    if (lane == 0) out[b] = val + fc2b[0];
}

extern "C" void kernel_launch(void* const* d_in, const int* in_sizes, int n_in,
                              void* d_out, int out_size, void* d_ws, size_t ws_size,
                              hipStream_t stream) {
    const float* x    = (const float*)d_in[0];
    const float* wih  = (const float*)d_in[1];
    const float* whh  = (const float*)d_in[2];
    const float* bih  = (const float*)d_in[3];
    const float* bhh  = (const float*)d_in[4];
    const float* fc1w = (const float*)d_in[5];
    const float* fc1b = (const float*)d_in[6];
    const float* fc2w = (const float*)d_in[7];
    const float* fc2b = (const float*)d_in[8];
    float* out = (float*)d_out;

    const int B = out_size;            // 4096
    dim3 grid(B / 4), block(256);
    hipLaunchKernelGGL(lstm_fused_kernel, grid, block, 0, stream,
                       x, wih, whh, bih, bhh, fc1w, fc1b, fc2w, fc2b, out);
}

// Round 9
// 343.232 us; speedup vs baseline: 1.2182x; 1.2182x over previous
//
#include <hip/hip_runtime.h>

#define TT 512
#define HH 32

typedef _Float16 f16x8 __attribute__((ext_vector_type(8)));
typedef float f32x4 __attribute__((ext_vector_type(4)));

__device__ __forceinline__ float fast_exp2(float v) { return __builtin_amdgcn_exp2f(v); }
__device__ __forceinline__ float fast_rcp(float v)  { return __builtin_amdgcn_rcpf(v); }

__global__ __launch_bounds__(64, 1) void lstm_mfma_kernel(
    const float* __restrict__ x,     // [B, T, 1]
    const float* __restrict__ wih,   // [128, 1]
    const float* __restrict__ whh,   // [128, 32]
    const float* __restrict__ bih,   // [128]
    const float* __restrict__ bhh,   // [128]
    const float* __restrict__ fc1w,  // [16, 32]
    const float* __restrict__ fc1b,  // [16]
    const float* __restrict__ fc2w,  // [1, 16]
    const float* __restrict__ fc2b,  // [1]
    float* __restrict__ out)         // [B, 1]
{
    __shared__ float    lds_xT[TT][16];   // x transposed: [t][batch], 32 KB
    __shared__ _Float16 lds_h[16][40];    // h exchange: [batch][unit], stride 40 (80B, 16B-aligned, pad kills conflicts)
    __shared__ float    lds_hf[16][32];   // final h f32 for MLP head

    const int lane = threadIdx.x;         // single wave per block
    const int b0 = blockIdx.x * 16;
    const int c  = lane & 15;             // batch col (B/C col = lane&15); also A row-within-tile
    const int q  = lane >> 4;             // k-group (and C row-group)

    // ---- stage x transposed into LDS: lds_xT[t][batch] ----
    {
        const int rb = lane >> 2;         // batch row 0..15
        const int m  = lane & 3;
        const float4* xr = reinterpret_cast<const float4*>(x + (size_t)(b0 + rb) * TT);
#pragma unroll 4
        for (int it = 0; it < 32; ++it) {
            const int idx = it * 4 + m;
            const float4 v = xr[idx];
            const int t0 = idx * 4;
            lds_xT[t0 + 0][rb] = v.x;
            lds_xT[t0 + 1][rb] = v.y;
            lds_xT[t0 + 2][rb] = v.z;
            lds_xT[t0 + 3][rb] = v.w;
        }
    }

    const float NK  = -1.4426950408889634f;   // -log2(e)
    const float NK2 = -2.8853900817779268f;   // -2*log2(e)

    // ---- A fragments: pre-scaled Whh, tile n = gate rows 16n..16n+15 ----
    // A[m][k]: m = lane&15 (row within tile), k = 8*(lane>>4) + j.
    // Scale -log2e folded in (x2 for g-rows, tiles 4,5) so activations skip the input mul.
    f16x8 afrag[8];
#pragma unroll
    for (int n = 0; n < 8; ++n) {
        const float s = (n == 4 || n == 5) ? NK2 : NK;
        const float* src = whh + (n * 16 + c) * HH + q * 8;
        f16x8 a;
#pragma unroll
        for (int j = 0; j < 8; ++j) a[j] = (_Float16)(s * src[j]);
        afrag[n] = a;
    }

    // ---- per-lane scaled wih / bias for accumulator init ----
    // C element (tile n, reg r) = gate gg = 16n + 4q + r of batch c.
    float wq[8][4], bq[8][4];
#pragma unroll
    for (int n = 0; n < 8; ++n) {
        const float s = (n == 4 || n == 5) ? NK2 : NK;
#pragma unroll
        for (int r = 0; r < 4; ++r) {
            const int gg = n * 16 + q * 4 + r;
            wq[n][r] = s * wih[gg];
            bq[n][r] = s * (bih[gg] + bhh[gg]);
        }
    }

    // B fragment: B[k][col] = h[batch=col][unit=k], k = 8q + j. H0 = 0.
    f16x8 bfrag;
#pragma unroll
    for (int j = 0; j < 8; ++j) bfrag[j] = (_Float16)0.0f;

    float cst[2][4];                      // c-state: unit u = 4q + r + 16p
#pragma unroll
    for (int p = 0; p < 2; ++p)
#pragma unroll
        for (int r = 0; r < 4; ++r) cst[p][r] = 0.0f;

    // (same-wave DS ops are in-order; staging writes complete before loop reads)

#pragma unroll 1
    for (int t = 0; t < TT; ++t) {
        const float xv = lds_xT[t][c];    // broadcast: 16 words, conflict-free

        f32x4 acc[8];
#pragma unroll
        for (int n = 0; n < 8; ++n) {
            f32x4 ini;
#pragma unroll
            for (int r = 0; r < 4; ++r) ini[r] = __builtin_fmaf(xv, wq[n][r], bq[n][r]);
            acc[n] = __builtin_amdgcn_mfma_f32_16x16x32_f16(afrag[n], bfrag, ini, 0, 0, 0);
        }

        // activations: gates of unit u = 4q+r+16p live in acc[type*2+p][r], all in this lane.
        // acc already holds -log2e*z (pre-scaled weights): sigmoid = rcp(1+exp2(.)),
        // tanh = 2*rcp(1+exp2(.)) - 1 (g rows pre-scaled by 2).
#pragma unroll
        for (int p = 0; p < 2; ++p) {
#pragma unroll
            for (int r = 0; r < 4; ++r) {
                const float iv = fast_rcp(1.0f + fast_exp2(acc[0 + p][r]));
                const float fv = fast_rcp(1.0f + fast_exp2(acc[2 + p][r]));
                const float gv = __builtin_fmaf(2.0f, fast_rcp(1.0f + fast_exp2(acc[4 + p][r])), -1.0f);
                const float ov = fast_rcp(1.0f + fast_exp2(acc[6 + p][r]));
                const float cc = __builtin_fmaf(fv, cst[p][r], iv * gv);
                cst[p][r] = cc;
                const float e  = fast_exp2(NK2 * cc);
                const float rr = fast_rcp(1.0f + e);
                const float hv = __builtin_fmaf(ov + ov, rr, -ov);   // o * tanh(c)
                lds_h[c][q * 4 + r + 16 * p] = (_Float16)hv;         // b16 write, ~2-way banks
            }
        }

        // rebuild B fragment for next step: contiguous 16B read (80B row stride, aligned)
        bfrag = *reinterpret_cast<const f16x8*>(&lds_h[c][q * 8]);
    }

    // ---- MLP head: bfrag holds final h[c][8q..8q+7] ----
#pragma unroll
    for (int j = 0; j < 8; ++j) lds_hf[c][q * 8 + j] = (float)bfrag[j];

    const int bat = lane >> 2;            // 4 lanes per batch
    const int mg  = lane & 3;             // each lane: 4 fc1 rows
    float val = 0.0f;
#pragma unroll
    for (int mm = 0; mm < 4; ++mm) {
        const int m = mg * 4 + mm;
        float s = fc1b[m];
        const float* fw = fc1w + m * HH;
#pragma unroll 8
        for (int u = 0; u < HH; ++u) s = __builtin_fmaf(lds_hf[bat][u], fw[u], s);
        val = __builtin_fmaf(fmaxf(s, 0.0f), fc2w[m], val);
    }
    val += __shfl_xor(val, 1);
    val += __shfl_xor(val, 2);
    if (mg == 0) out[b0 + bat] = val + fc2b[0];
}

extern "C" void kernel_launch(void* const* d_in, const int* in_sizes, int n_in,
                              void* d_out, int out_size, void* d_ws, size_t ws_size,
                              hipStream_t stream) {
    const float* x    = (const float*)d_in[0];
    const float* wih  = (const float*)d_in[1];
    const float* whh  = (const float*)d_in[2];
    const float* bih  = (const float*)d_in[3];
    const float* bhh  = (const float*)d_in[4];
    const float* fc1w = (const float*)d_in[5];
    const float* fc1b = (const float*)d_in[6];
    const float* fc2w = (const float*)d_in[7];
    const float* fc2b = (const float*)d_in[8];
    float* out = (float*)d_out;

    const int B = out_size;               // 4096
    dim3 grid(B / 16), block(64);         // 256 one-wave blocks -> 1 per CU
    hipLaunchKernelGGL(lstm_mfma_kernel, grid, block, 0, stream,
                       x, wih, whh, bih, bhh, fc1w, fc1b, fc2w, fc2b, out);
}

// Round 10
// 251.987 us; speedup vs baseline: 1.6593x; 1.3621x over previous
//
#include <hip/hip_runtime.h>

#define TT 512
#define HH 32

typedef _Float16 f16x8 __attribute__((ext_vector_type(8)));
typedef float f32x4 __attribute__((ext_vector_type(4)));

__device__ __forceinline__ float fast_exp2(float v) { return __builtin_amdgcn_exp2f(v); }
__device__ __forceinline__ float fast_rcp(float v)  { return __builtin_amdgcn_rcpf(v); }

__global__ __launch_bounds__(256, 1) void lstm_mfma4_kernel(
    const float* __restrict__ x,     // [B, T, 1]
    const float* __restrict__ wih,   // [128, 1]
    const float* __restrict__ whh,   // [128, 32]
    const float* __restrict__ bih,   // [128]
    const float* __restrict__ bhh,   // [128]
    const float* __restrict__ fc1w,  // [16, 32]
    const float* __restrict__ fc1b,  // [16]
    const float* __restrict__ fc2w,  // [1, 16]
    const float* __restrict__ fc2b,  // [1]
    float* __restrict__ out)         // [B, 1]
{
    __shared__ float    lds_xT[TT][16];     // x transposed: [t][batch], 32 KB
    __shared__ _Float16 lds_h[2][16][40];   // double-buffered h: [buf][batch][unit], stride 40
    __shared__ float    lds_hf[16][32];     // final h f32 for MLP head

    const int tid  = threadIdx.x;
    const int wv   = tid >> 6;              // wave 0..3 — owns acc reg r == wv
    const int lane = tid & 63;
    const int b0 = blockIdx.x * 16;
    const int c  = lane & 15;               // batch col
    const int q  = lane >> 4;               // k-group / C row-group

    // ---- stage x transposed into LDS with all 256 threads ----
    {
        const int rb = tid >> 4;            // batch 0..15
        const int m  = tid & 15;
        const float4* xr = reinterpret_cast<const float4*>(x + (size_t)(b0 + rb) * TT);
#pragma unroll
        for (int it = 0; it < 8; ++it) {
            const int idx = it * 16 + m;    // float4 index 0..127
            const float4 v = xr[idx];
            const int t0 = idx * 4;
            lds_xT[t0 + 0][rb] = v.x;
            lds_xT[t0 + 1][rb] = v.y;
            lds_xT[t0 + 2][rb] = v.z;
            lds_xT[t0 + 3][rb] = v.w;
        }
    }

    const float NK  = -1.4426950408889634f;   // -log2(e)
    const float NK2 = -2.8853900817779268f;   // -2*log2(e)

    // ---- A fragments: pre-scaled Whh (every wave loads all 8 tiles) ----
    f16x8 afrag[8];
#pragma unroll
    for (int n = 0; n < 8; ++n) {
        const float s = (n == 4 || n == 5) ? NK2 : NK;
        const float* src = whh + (n * 16 + c) * HH + q * 8;
        f16x8 a;
#pragma unroll
        for (int j = 0; j < 8; ++j) a[j] = (_Float16)(s * src[j]);
        afrag[n] = a;
    }

    // ---- per-lane scaled wih / bias for accumulator init (all 8 tiles) ----
    float wq[8][4], bq[8][4];
#pragma unroll
    for (int n = 0; n < 8; ++n) {
        const float s = (n == 4 || n == 5) ? NK2 : NK;
#pragma unroll
        for (int r = 0; r < 4; ++r) {
            const int gg = n * 16 + q * 4 + r;
            wq[n][r] = s * wih[gg];
            bq[n][r] = s * (bih[gg] + bhh[gg]);
        }
    }

    // B fragment: B[k][col] = h[batch=col][unit=k]; H0 = 0
    f16x8 bfrag;
#pragma unroll
    for (int j = 0; j < 8; ++j) bfrag[j] = (_Float16)0.0f;

    float cst[2] = {0.0f, 0.0f};            // c-state for units 4q+wv, 4q+wv+16

    __syncthreads();                        // x staged

#pragma unroll 1
    for (int t = 0; t < TT; ++t) {
        const float xv = lds_xT[t][c];

        f32x4 acc[8];
#pragma unroll
        for (int n = 0; n < 8; ++n) {
            f32x4 ini;
#pragma unroll
            for (int r = 0; r < 4; ++r) ini[r] = __builtin_fmaf(xv, wq[n][r], bq[n][r]);
            acc[n] = __builtin_amdgcn_mfma_f32_16x16x32_f16(afrag[n], bfrag, ini, 0, 0, 0);
        }

        // cell update only for reg r == wv (wave-uniform branch, static indices)
        _Float16* hrow = &lds_h[t & 1][c][0];
#pragma unroll
        for (int r = 0; r < 4; ++r) {
            if (wv == r) {
#pragma unroll
                for (int p = 0; p < 2; ++p) {
                    const float iv = fast_rcp(1.0f + fast_exp2(acc[0 + p][r]));
                    const float fv = fast_rcp(1.0f + fast_exp2(acc[2 + p][r]));
                    const float gv = __builtin_fmaf(2.0f, fast_rcp(1.0f + fast_exp2(acc[4 + p][r])), -1.0f);
                    const float ov = fast_rcp(1.0f + fast_exp2(acc[6 + p][r]));
                    const float cc = __builtin_fmaf(fv, cst[p], iv * gv);
                    cst[p] = cc;
                    const float e  = fast_exp2(NK2 * cc);
                    const float rr = fast_rcp(1.0f + e);
                    const float hv = __builtin_fmaf(ov + ov, rr, -ov);   // o * tanh(c)
                    hrow[q * 4 + r + 16 * p] = (_Float16)hv;
                }
            }
        }

        __syncthreads();                    // h(t+1) complete; prior buf reads done

        bfrag = *reinterpret_cast<const f16x8*>(&lds_h[t & 1][c][q * 8]);
    }

    // ---- MLP head on wave 0 (bfrag identical in all waves) ----
    if (wv == 0) {
#pragma unroll
        for (int j = 0; j < 8; ++j) lds_hf[c][q * 8 + j] = (float)bfrag[j];

        const int bat = lane >> 2;          // 4 lanes per batch
        const int mg  = lane & 3;           // each lane: 4 fc1 rows
        float val = 0.0f;
#pragma unroll
        for (int mm = 0; mm < 4; ++mm) {
            const int m = mg * 4 + mm;
            float s = fc1b[m];
            const float* fw = fc1w + m * HH;
#pragma unroll 8
            for (int u = 0; u < HH; ++u) s = __builtin_fmaf(lds_hf[bat][u], fw[u], s);
            val = __builtin_fmaf(fmaxf(s, 0.0f), fc2w[m], val);
        }
        val += __shfl_xor(val, 1);
        val += __shfl_xor(val, 2);
        if (mg == 0) out[b0 + bat] = val + fc2b[0];
    }
}

extern "C" void kernel_launch(void* const* d_in, const int* in_sizes, int n_in,
                              void* d_out, int out_size, void* d_ws, size_t ws_size,
                              hipStream_t stream) {
    const float* x    = (const float*)d_in[0];
    const float* wih  = (const float*)d_in[1];
    const float* whh  = (const float*)d_in[2];
    const float* bih  = (const float*)d_in[3];
    const float* bhh  = (const float*)d_in[4];
    const float* fc1w = (const float*)d_in[5];
    const float* fc1b = (const float*)d_in[6];
    const float* fc2w = (const float*)d_in[7];
    const float* fc2b = (const float*)d_in[8];
    float* out = (float*)d_out;

    const int B = out_size;                 // 4096
    dim3 grid(B / 16), block(256);          // 256 blocks × 4 waves -> 4 waves/CU
    hipLaunchKernelGGL(lstm_mfma4_kernel, grid, block, 0, stream,
                       x, wih, whh, bih, bhh, fc1w, fc1b, fc2w, fc2b, out);
}

// Round 11
// 234.646 us; speedup vs baseline: 1.7819x; 1.0739x over previous
//
#include <hip/hip_runtime.h>

#define TT 512

typedef _Float16 f16x8 __attribute__((ext_vector_type(8)));
typedef float f32x4 __attribute__((ext_vector_type(4)));

__device__ __forceinline__ float fast_exp2(float v) { return __builtin_amdgcn_exp2f(v); }
__device__ __forceinline__ float fast_rcp(float v)  { return __builtin_amdgcn_rcpf(v); }

__global__ __launch_bounds__(256, 2) void lstm_mfma8_kernel(
    const float* __restrict__ x,     // [B, T, 1]
    const float* __restrict__ wih,   // [128, 1]
    const float* __restrict__ whh,   // [128, 32]
    const float* __restrict__ bih,   // [128]
    const float* __restrict__ bhh,   // [128]
    const float* __restrict__ fc1w,  // [16, 32]
    const float* __restrict__ fc1b,  // [16]
    const float* __restrict__ fc2w,  // [1, 16]
    const float* __restrict__ fc2b,  // [1]
    float* __restrict__ out)         // [B, 1]
{
    __shared__ float    lds_xT[TT + 1][8];   // x transposed (8 real batches), row TT zeroed for prefetch
    __shared__ _Float16 lds_h[2][16][40];    // double-buffered h: [buf][col][unit], stride 40
    __shared__ float    lds_hf[8][32];       // final h f32 for MLP head

    const int tid  = threadIdx.x;
    const int wv   = tid >> 6;               // wave 0..3 — owns acc reg r == wv
    const int lane = tid & 63;
    const int b0 = blockIdx.x * 8;
    const int c  = lane & 15;                // MFMA col; cols 8-15 duplicate batches 0-7
    const int cb = c & 7;                    // real batch index for x
    const int q  = lane >> 4;                // k-group / C row-group

    // ---- stage x rows b0..b0+7 transposed into LDS ----
    {
        const int rb = tid >> 5;             // batch 0..7
        const int m  = tid & 31;
        const float4* xr = reinterpret_cast<const float4*>(x + (size_t)(b0 + rb) * TT);
#pragma unroll
        for (int it = 0; it < 4; ++it) {
            const int idx = it * 32 + m;     // float4 index 0..127
            const float4 v = xr[idx];
            const int t0 = idx * 4;
            lds_xT[t0 + 0][rb] = v.x;
            lds_xT[t0 + 1][rb] = v.y;
            lds_xT[t0 + 2][rb] = v.z;
            lds_xT[t0 + 3][rb] = v.w;
        }
        if (tid < 8) lds_xT[TT][tid] = 0.0f;
    }

    const float NK  = -1.4426950408889634f;  // -log2(e)
    const float NK2 = -2.8853900817779268f;  // -2*log2(e)

    // ---- A fragments: pre-scaled Whh (tile n = gate rows 16n..16n+15) ----
    f16x8 afrag[8];
#pragma unroll
    for (int n = 0; n < 8; ++n) {
        const float s = (n == 4 || n == 5) ? NK2 : NK;
        const float* src = whh + (n * 16 + c) * 32 + q * 8;
        f16x8 a;
#pragma unroll
        for (int j = 0; j < 8; ++j) a[j] = (_Float16)(s * src[j]);
        afrag[n] = a;
    }

    // ---- own-r scaled wih / bias (gate gg = 16n + 4q + wv) ----
    float wqr[8], bqr[8];
#pragma unroll
    for (int n = 0; n < 8; ++n) {
        const float s = (n == 4 || n == 5) ? NK2 : NK;
        const int gg = n * 16 + q * 4 + wv;
        wqr[n] = s * wih[gg];
        bqr[n] = s * (bih[gg] + bhh[gg]);
    }

    f16x8 bfrag;
#pragma unroll
    for (int j = 0; j < 8; ++j) bfrag[j] = (_Float16)0.0f;

    float cst0 = 0.0f, cst1 = 0.0f;          // c-state for units 4q+wv (p=0), 4q+wv+16 (p=1)
    const f32x4 zero4 = {0.0f, 0.0f, 0.0f, 0.0f};

    __syncthreads();                         // x staged
    float xv = lds_xT[0][cb];

#pragma unroll 1
    for (int t = 0; t < TT; ++t) {
        f32x4 acc[8];
#pragma unroll
        for (int n = 0; n < 8; ++n)
            acc[n] = __builtin_amdgcn_mfma_f32_16x16x32_f16(afrag[n], bfrag, zero4, 0, 0, 0);

        const float xnext = lds_xT[t + 1][cb];   // prefetch (overlaps MFMA/activation/barrier)

        _Float16* hrow = &lds_h[t & 1][c][0];
#pragma unroll
        for (int r = 0; r < 4; ++r) {
            if (wv == r) {                       // wave-uniform; static acc indices
#pragma unroll
                for (int p = 0; p < 2; ++p) {
                    const float Ai = __builtin_fmaf(xv, wqr[0 + p], bqr[0 + p]) + acc[0 + p][r];
                    const float Af = __builtin_fmaf(xv, wqr[2 + p], bqr[2 + p]) + acc[2 + p][r];
                    const float Ag = __builtin_fmaf(xv, wqr[4 + p], bqr[4 + p]) + acc[4 + p][r];
                    const float Ao = __builtin_fmaf(xv, wqr[6 + p], bqr[6 + p]) + acc[6 + p][r];
                    const float ei = fast_exp2(Ai);
                    const float ef = fast_exp2(Af);
                    const float eg = fast_exp2(Ag);
                    const float eo = fast_exp2(Ao);
                    // c' = (c*(1+ei)(1+eg) + (1-eg)(1+ef)) / ((1+ei)(1+eg)(1+ef))
                    const float P  = (1.0f + ei) * (1.0f + eg);
                    const float Bf = 1.0f + ef;
                    float& cs = p ? cst1 : cst0;
                    const float N  = __builtin_fmaf(cs, P, (1.0f - eg) * Bf);
                    const float cn = N * fast_rcp(P * Bf);
                    cs = cn;
                    // h = (1-ec) / ((1+ec)(1+eo))
                    const float ec = fast_exp2(NK2 * cn);
                    const float hv = (1.0f - ec) * fast_rcp((1.0f + eo) * (1.0f + ec));
                    hrow[q * 4 + r + 16 * p] = (_Float16)hv;
                }
            }
        }

        __syncthreads();                     // h(t) complete for all waves
        bfrag = *reinterpret_cast<const f16x8*>(&lds_h[t & 1][c][q * 8]);
        xv = xnext;
    }

    // ---- MLP head on wave 0 (bfrag holds final h[c][8q..8q+7]) ----
    if (wv == 0) {
        if (c < 8) {
#pragma unroll
            for (int j = 0; j < 8; ++j) lds_hf[c][q * 8 + j] = (float)bfrag[j];
        }
        // same-wave LDS write->read is in-order; no barrier needed
        const int bat = lane >> 2;           // 4 lanes per batch (0..15; 8-15 idle)
        const int mg  = lane & 3;
        float val = 0.0f;
#pragma unroll
        for (int mm = 0; mm < 4; ++mm) {
            const int m = mg * 4 + mm;
            float s = fc1b[m];
            const float* fw = fc1w + m * 32;
#pragma unroll 8
            for (int u = 0; u < 32; ++u) s = __builtin_fmaf(lds_hf[bat & 7][u], fw[u], s);
            val = __builtin_fmaf(fmaxf(s, 0.0f), fc2w[m], val);
        }
        val += __shfl_xor(val, 1);
        val += __shfl_xor(val, 2);
        if (mg == 0 && bat < 8) out[b0 + bat] = val + fc2b[0];
    }
}

extern "C" void kernel_launch(void* const* d_in, const int* in_sizes, int n_in,
                              void* d_out, int out_size, void* d_ws, size_t ws_size,
                              hipStream_t stream) {
    const float* x    = (const float*)d_in[0];
    const float* wih  = (const float*)d_in[1];
    const float* whh  = (const float*)d_in[2];
    const float* bih  = (const float*)d_in[3];
    const float* bhh  = (const float*)d_in[4];
    const float* fc1w = (const float*)d_in[5];
    const float* fc1b = (const float*)d_in[6];
    const float* fc2w = (const float*)d_in[7];
    const float* fc2b = (const float*)d_in[8];
    float* out = (float*)d_out;

    const int B = out_size;                  // 4096
    dim3 grid(B / 8), block(256);            // 512 blocks -> 2 independent chains per CU
    hipLaunchKernelGGL(lstm_mfma8_kernel, grid, block, 0, stream,
                       x, wih, whh, bih, bhh, fc1w, fc1b, fc2w, fc2b, out);
}